// Round 2
// baseline (446.869 us; speedup 1.0000x reference)
//
#include <hip/hip_runtime.h>
#include <cstdint>
#include <cstddef>

typedef unsigned short u16;
typedef short short8 __attribute__((ext_vector_type(8)));
typedef float floatx4 __attribute__((ext_vector_type(4)));

__device__ __forceinline__ float bf2f(u16 u) {
    union { unsigned int i; float f; } v; v.i = ((unsigned int)u) << 16; return v.f;
}
__device__ __forceinline__ u16 f2bf(float f) {
    union { float f; unsigned int i; } v; v.f = f;
    unsigned int u = v.i;
    return (u16)((u + 0x7fffu + ((u >> 16) & 1u)) >> 16);
}

// ---------------------------------------------------------------------------
// Convert+transpose 4 weight matrices (E x E, f32) -> bf16 ws. Wt[n][k]=W[k][n].
// ---------------------------------------------------------------------------
__global__ void conv_transpose_k(const float* __restrict__ w0, const float* __restrict__ w1,
                                 const float* __restrict__ w2, const float* __restrict__ w3,
                                 u16* __restrict__ o0, u16* __restrict__ o1,
                                 u16* __restrict__ o2, u16* __restrict__ o3, int n) {
    __shared__ float t[32][33];
    const float* w; u16* o;
    switch (blockIdx.z) {
        case 0: w = w0; o = o0; break;
        case 1: w = w1; o = o1; break;
        case 2: w = w2; o = o2; break;
        default: w = w3; o = o3; break;
    }
    int tx = threadIdx.x, ty = threadIdx.y;
    int x0 = blockIdx.x * 32, y0 = blockIdx.y * 32;
    t[ty][tx] = w[(size_t)(y0 + ty) * n + x0 + tx];
    __syncthreads();
    o[(size_t)(x0 + ty) * n + y0 + tx] = f2bf(t[tx][ty]);
}

// ---------------------------------------------------------------------------
// Convert f32 -> bf16, vectorized (n multiple of 1024).
// ---------------------------------------------------------------------------
__global__ void conv_k(const float* __restrict__ in, u16* __restrict__ out, int n) {
    int i = (blockIdx.x * blockDim.x + threadIdx.x) * 4;
    if (i >= n) return;
    float4 v = *(const float4*)&in[i];
    ushort4 o;
    o.x = f2bf(v.x); o.y = f2bf(v.y); o.z = f2bf(v.z); o.w = f2bf(v.w);
    *(ushort4*)&out[i] = o;
}

// ---------------------------------------------------------------------------
// C[M,N] = A[M,K] @ Bt[N,K]^T, bf16 in, f32 accum.
// Block tile 128x128, BK=32. 256 threads = 4 waves, each wave 64x64 (4x4
// MFMA 16x16x32 tiles).
// EPI==0: C = Cb (bf16) = acc.
// EPI==1: C = Cf (f32)  = bf2f(resid) + relu(acc + bias[col]).
// ---------------------------------------------------------------------------
template <int EPI>
__global__ __launch_bounds__(256) void gemm_bt(
    const u16* __restrict__ A, const u16* __restrict__ Bt,
    u16* __restrict__ Cb, float* __restrict__ Cf,
    const float* __restrict__ bias, const u16* __restrict__ resid,
    int M, int N, int K) {
    __shared__ u16 lds_a[128][32];
    __shared__ u16 lds_b[128][32];

    const int tid = threadIdx.x;
    const int lane = tid & 63, wave = tid >> 6;
    const int wm = (wave >> 1) * 64, wn = (wave & 1) * 64;
    const int bm = blockIdx.x * 128, bn = blockIdx.y * 128;
    const int l15 = lane & 15, lq = lane >> 4;

    floatx4 acc[4][4];
#pragma unroll
    for (int i = 0; i < 4; ++i)
#pragma unroll
        for (int j = 0; j < 4; ++j) acc[i][j] = (floatx4)0.0f;

    for (int k0 = 0; k0 < K; k0 += 32) {
#pragma unroll
        for (int it = 0; it < 2; ++it) {
            int idx = it * 256 + tid;        // 0..511
            int row = idx >> 2;              // 0..127
            int c8 = (idx & 3) * 8;          // 0,8,16,24
            *(uint4*)&lds_a[row][c8] = *(const uint4*)&A[(size_t)(bm + row) * K + k0 + c8];
            *(uint4*)&lds_b[row][c8] = *(const uint4*)&Bt[(size_t)(bn + row) * K + k0 + c8];
        }
        __syncthreads();

        short8 af[4], bfr[4];
#pragma unroll
        for (int i = 0; i < 4; ++i) af[i] = *(const short8*)&lds_a[wm + i * 16 + l15][lq * 8];
#pragma unroll
        for (int j = 0; j < 4; ++j) bfr[j] = *(const short8*)&lds_b[wn + j * 16 + l15][lq * 8];

#pragma unroll
        for (int i = 0; i < 4; ++i)
#pragma unroll
            for (int j = 0; j < 4; ++j)
                acc[i][j] = __builtin_amdgcn_mfma_f32_16x16x32_bf16(af[i], bfr[j], acc[i][j], 0, 0, 0);
        __syncthreads();
    }

#pragma unroll
    for (int i = 0; i < 4; ++i)
#pragma unroll
        for (int j = 0; j < 4; ++j)
#pragma unroll
            for (int r = 0; r < 4; ++r) {
                int row = bm + wm + i * 16 + lq * 4 + r;
                int col = bn + wn + j * 16 + l15;
                float v = acc[i][j][r];
                if (EPI == 0) {
                    Cb[(size_t)row * N + col] = f2bf(v);
                } else {
                    v = fmaxf(v + bias[col], 0.0f) + bf2f(resid[(size_t)row * N + col]);
                    Cf[(size_t)row * N + col] = v;
                }
            }
}

// ---------------------------------------------------------------------------
// Flash attention, causal, scale = 1/sqrt(E) = 1/32. One wave handles a
// 16-row Q tile of one (b,h); block = 4 waves = 64 q rows. Writes
// y = x + attn as bf16 (x read from f32).
// ---------------------------------------------------------------------------
__global__ __launch_bounds__(256) void attn_k(
    const u16* __restrict__ q, const u16* __restrict__ k, const u16* __restrict__ v,
    const float* __restrict__ xf, u16* __restrict__ y, int T, int E) {
    __shared__ u16 lds_p[4][16][32];

    const int tid = threadIdx.x;
    const int lane = tid & 63, wave = tid >> 6;
    const int l15 = lane & 15, lq = lane >> 4;
    const int bh = blockIdx.y;
    const int b = bh >> 4, h = bh & 15;
    const int qt0 = blockIdx.x * 64;
    const int qt = qt0 + wave * 16;

    const size_t base = (size_t)b * T * E + (size_t)h * 64;
    const u16* qp = q + base;
    const u16* kp = k + base;
    const u16* vp = v + base;

    // Q fragments: A-layout, two 32-wide K-chunks over dh=64
    short8 aq[2];
#pragma unroll
    for (int c = 0; c < 2; ++c)
        aq[c] = *(const short8*)&qp[(size_t)(qt + l15) * E + c * 32 + lq * 8];

    floatx4 o[4];
#pragma unroll
    for (int n = 0; n < 4; ++n) o[n] = (floatx4)0.0f;
    float mrow[4], lrow[4];
#pragma unroll
    for (int r = 0; r < 4; ++r) { mrow[r] = -3.0e38f; lrow[r] = 0.0f; }

    const int nkb = (qt0 + 64) >> 5;  // 32-wide K chunks covering cols 0..qt0+63
    for (int kt = 0; kt < nkb; ++kt) {
        const int kcol0 = kt * 32;

        // S = Q K^T for 16 q-rows x 32 k-cols (two 16-col subtiles)
        floatx4 s[2];
#pragma unroll
        for (int t2 = 0; t2 < 2; ++t2) {
            floatx4 sa = (floatx4)0.0f;
#pragma unroll
            for (int c = 0; c < 2; ++c) {
                short8 bk = *(const short8*)&kp[(size_t)(kcol0 + t2 * 16 + l15) * E + c * 32 + lq * 8];
                sa = __builtin_amdgcn_mfma_f32_16x16x32_bf16(aq[c], bk, sa, 0, 0, 0);
            }
            s[t2] = sa;
        }

        // scale + causal mask
#pragma unroll
        for (int t2 = 0; t2 < 2; ++t2)
#pragma unroll
            for (int r = 0; r < 4; ++r) {
                int colg = kcol0 + t2 * 16 + l15;
                int rowg = qt + lq * 4 + r;
                float val = s[t2][r] * 0.03125f;
                s[t2][r] = (colg <= rowg) ? val : -3.0e38f;
            }

        // online softmax per q-row (each row's 16 cols live on one 16-lane group)
#pragma unroll
        for (int r = 0; r < 4; ++r) {
            float mv = fmaxf(s[0][r], s[1][r]);
#pragma unroll
            for (int msk = 1; msk < 16; msk <<= 1) mv = fmaxf(mv, __shfl_xor(mv, msk, 64));
            float mnew = fmaxf(mrow[r], mv);
            float alpha = __expf(mrow[r] - mnew);
            float p0 = __expf(s[0][r] - mnew);
            float p1 = __expf(s[1][r] - mnew);
            float sum = p0 + p1;
#pragma unroll
            for (int msk = 1; msk < 16; msk <<= 1) sum += __shfl_xor(sum, msk, 64);
            lrow[r] = lrow[r] * alpha + sum;
            mrow[r] = mnew;
#pragma unroll
            for (int n = 0; n < 4; ++n) o[n][r] *= alpha;
            lds_p[wave][lq * 4 + r][l15] = f2bf(p0);
            lds_p[wave][lq * 4 + r][16 + l15] = f2bf(p1);
        }
        __syncthreads();  // order P writes (C-layout) before A-layout reads

        // P (16x32) @ V (32x64) -> O, four 16-col d chunks
        short8 ap = *(const short8*)&lds_p[wave][l15][lq * 8];
#pragma unroll
        for (int n = 0; n < 4; ++n) {
            short8 bv;
#pragma unroll
            for (int jj = 0; jj < 8; ++jj)
                bv[jj] = (short)vp[(size_t)(kcol0 + lq * 8 + jj) * E + n * 16 + l15];
            o[n] = __builtin_amdgcn_mfma_f32_16x16x32_bf16(ap, bv, o[n], 0, 0, 0);
        }
        __syncthreads();  // P reads done before next iteration overwrites
    }

    // epilogue: y = x + O/l (bf16 out, f32 residual in)
    const float* xp = xf + base;
    u16* yp = y + base;
#pragma unroll
    for (int n = 0; n < 4; ++n)
#pragma unroll
        for (int r = 0; r < 4; ++r) {
            int rowg = qt + lq * 4 + r;
            int col = n * 16 + l15;
            float val = o[n][r] / lrow[r];
            float res = xp[(size_t)rowg * E + col];
            yp[(size_t)rowg * E + col] = f2bf(res + val);
        }
}

// ---------------------------------------------------------------------------
extern "C" void kernel_launch(void* const* d_in, const int* in_sizes, int n_in,
                              void* d_out, int out_size, void* d_ws, size_t ws_size,
                              hipStream_t stream) {
    const int B = 2, T = 2048, E = 1024;
    const int M = B * T;  // 4096

    const float* x  = (const float*)d_in[0];
    const float* Wq = (const float*)d_in[1];
    const float* Wk = (const float*)d_in[2];
    const float* Wv = (const float*)d_in[3];
    const float* Wf = (const float*)d_in[4];
    const float* bf = (const float*)d_in[5];
    float* out = (float*)d_out;

    u16* ws = (u16*)d_ws;
    const size_t WN = (size_t)E * E;      // 1M elems per weight
    const size_t XN = (size_t)M * E;      // 4M elems per activation
    u16* WqT = ws;
    u16* WkT = ws + WN;
    u16* WvT = ws + 2 * WN;
    u16* WfT = ws + 3 * WN;
    u16* xb  = ws + 4 * WN;
    u16* qb  = xb + XN;
    u16* kb  = qb + XN;
    u16* vb  = kb + XN;
    u16* yb  = vb + XN;

    conv_transpose_k<<<dim3(E / 32, E / 32, 4), dim3(32, 32), 0, stream>>>(
        Wq, Wk, Wv, Wf, WqT, WkT, WvT, WfT, E);
    conv_k<<<(int)(XN / 1024), 256, 0, stream>>>(x, xb, (int)XN);

    dim3 gb(M / 128, E / 128);  // 32 x 8
    gemm_bt<0><<<gb, 256, 0, stream>>>(xb, WqT, qb, nullptr, nullptr, nullptr, M, E, E);
    gemm_bt<0><<<gb, 256, 0, stream>>>(xb, WkT, kb, nullptr, nullptr, nullptr, M, E, E);
    gemm_bt<0><<<gb, 256, 0, stream>>>(xb, WvT, vb, nullptr, nullptr, nullptr, M, E, E);

    attn_k<<<dim3(T / 64, B * 16), 256, 0, stream>>>(qb, kb, vb, x, yb, T, E);

    gemm_bt<1><<<gb, 256, 0, stream>>>(yb, WfT, nullptr, out, bf, yb, M, E, E);
}

// Round 3
// 356.175 us; speedup vs baseline: 1.2546x; 1.2546x over previous
//
#include <hip/hip_runtime.h>
#include <cstdint>
#include <cstddef>

typedef unsigned short u16;
typedef short short8 __attribute__((ext_vector_type(8)));
typedef float floatx4 __attribute__((ext_vector_type(4)));

__device__ __forceinline__ float bf2f(u16 u) {
    union { unsigned int i; float f; } v; v.i = ((unsigned int)u) << 16; return v.f;
}
__device__ __forceinline__ u16 f2bf(float f) {
    union { float f; unsigned int i; } v; v.f = f;
    unsigned int u = v.i;
    return (u16)((u + 0x7fffu + ((u >> 16) & 1u)) >> 16);
}

#if __has_builtin(__builtin_amdgcn_exp2f)
#define EXP2F(x) __builtin_amdgcn_exp2f(x)
#else
#define EXP2F(x) exp2f(x)
#endif

// async global->LDS, 16B per lane; LDS dest = wave-uniform base + lane*16
__device__ __forceinline__ void gload_lds16(const u16* g, void* lds_wave_base) {
    __builtin_amdgcn_global_load_lds(
        (__attribute__((address_space(1))) void*)g,
        (__attribute__((address_space(3))) void*)lds_wave_base,
        16, 0, 0);
}

// ---------------------------------------------------------------------------
// Convert+transpose 4 weight matrices (E x E, f32) -> bf16. Wt[n][k]=W[k][n].
// ---------------------------------------------------------------------------
__global__ void conv_transpose_k(const float* __restrict__ w0, const float* __restrict__ w1,
                                 const float* __restrict__ w2, const float* __restrict__ w3,
                                 u16* __restrict__ o0, u16* __restrict__ o1,
                                 u16* __restrict__ o2, u16* __restrict__ o3, int n) {
    __shared__ float t[32][33];
    const float* w; u16* o;
    switch (blockIdx.z) {
        case 0: w = w0; o = o0; break;
        case 1: w = w1; o = o1; break;
        case 2: w = w2; o = o2; break;
        default: w = w3; o = o3; break;
    }
    int tx = threadIdx.x, ty = threadIdx.y;
    int x0 = blockIdx.x * 32, y0 = blockIdx.y * 32;
    t[ty][tx] = w[(size_t)(y0 + ty) * n + x0 + tx];
    __syncthreads();
    o[(size_t)(x0 + ty) * n + y0 + tx] = f2bf(t[tx][ty]);
}

// ---------------------------------------------------------------------------
// Convert f32 -> bf16, vectorized.
// ---------------------------------------------------------------------------
__global__ void conv_k(const float* __restrict__ in, u16* __restrict__ out, int n) {
    int i = (blockIdx.x * blockDim.x + threadIdx.x) * 4;
    if (i >= n) return;
    float4 v = *(const float4*)&in[i];
    ushort4 o;
    o.x = f2bf(v.x); o.y = f2bf(v.y); o.z = f2bf(v.z); o.w = f2bf(v.w);
    *(ushort4*)&out[i] = o;
}

// ---------------------------------------------------------------------------
// Per-head V transpose: vt[(b*16+h)*64 + d][t] = v[(b*T+t)*E + h*64 + d]
// grid (T/32, 64/32, B*H), block (32,32)
// ---------------------------------------------------------------------------
__global__ void vtrans_k(const u16* __restrict__ v, u16* __restrict__ vt, int T, int E) {
    __shared__ u16 t[32][33];
    int bh = blockIdx.z;
    int b = bh >> 4, h = bh & 15;
    int t0 = blockIdx.x * 32, d0 = blockIdx.y * 32;
    int tx = threadIdx.x, ty = threadIdx.y;
    t[ty][tx] = v[(size_t)(b * T + t0 + ty) * E + h * 64 + d0 + tx];
    __syncthreads();
    vt[((size_t)bh * 64 + d0 + ty) * T + t0 + tx] = t[tx][ty];
}

// ---------------------------------------------------------------------------
// C[M,N] = A[M,K] @ Bt[N,K]^T, bf16 in, f32 accum.
// 128x128 tile, BK=32, 4 waves x (4x4) 16x16x32 MFMA. global_load_lds staging.
// EPI==0: Cb (bf16) = acc.  EPI==1: Cf (f32) = bf2f(resid)+relu(acc+bias[col]).
// ---------------------------------------------------------------------------
template <int EPI>
__global__ __launch_bounds__(256) void gemm_bt(
    const u16* __restrict__ A, const u16* __restrict__ Bt,
    u16* __restrict__ Cb, float* __restrict__ Cf,
    const float* __restrict__ bias, const u16* __restrict__ resid,
    int M, int N, int K) {
    __shared__ u16 lds_a[128][32];
    __shared__ u16 lds_b[128][32];

    const int tid = threadIdx.x;
    const int lane = tid & 63, wave = tid >> 6;
    const int wm = (wave >> 1) * 64, wn = (wave & 1) * 64;
    const int bm = blockIdx.x * 128, bn = blockIdx.y * 128;
    const int l15 = lane & 15, lq = lane >> 4;

    floatx4 acc[4][4];
#pragma unroll
    for (int i = 0; i < 4; ++i)
#pragma unroll
        for (int j = 0; j < 4; ++j) acc[i][j] = (floatx4)0.0f;

    for (int k0 = 0; k0 < K; k0 += 32) {
#pragma unroll
        for (int it = 0; it < 2; ++it) {
            int idx = it * 256 + tid;        // 0..511
            int row = idx >> 2;              // 0..127
            int c8 = (idx & 3) * 8;          // 0,8,16,24
            size_t ldsoff = (size_t)(it * 256 + wave * 64) * 16;  // bytes, wave-uniform
            gload_lds16(&A[(size_t)(bm + row) * K + k0 + c8], (char*)&lds_a[0][0] + ldsoff);
            gload_lds16(&Bt[(size_t)(bn + row) * K + k0 + c8], (char*)&lds_b[0][0] + ldsoff);
        }
        __syncthreads();

        short8 af[4], bfr[4];
#pragma unroll
        for (int i = 0; i < 4; ++i) af[i] = *(const short8*)&lds_a[wm + i * 16 + l15][lq * 8];
#pragma unroll
        for (int j = 0; j < 4; ++j) bfr[j] = *(const short8*)&lds_b[wn + j * 16 + l15][lq * 8];

#pragma unroll
        for (int i = 0; i < 4; ++i)
#pragma unroll
            for (int j = 0; j < 4; ++j)
                acc[i][j] = __builtin_amdgcn_mfma_f32_16x16x32_bf16(af[i], bfr[j], acc[i][j], 0, 0, 0);
        __syncthreads();
    }

#pragma unroll
    for (int i = 0; i < 4; ++i)
#pragma unroll
        for (int j = 0; j < 4; ++j)
#pragma unroll
            for (int r = 0; r < 4; ++r) {
                int row = bm + wm + i * 16 + lq * 4 + r;
                int col = bn + wn + j * 16 + l15;
                float v = acc[i][j][r];
                if (EPI == 0) {
                    Cb[(size_t)row * N + col] = f2bf(v);
                } else {
                    v = fmaxf(v + bias[col], 0.0f) + bf2f(resid[(size_t)row * N + col]);
                    Cf[(size_t)row * N + col] = v;
                }
            }
}

// ---------------------------------------------------------------------------
// Flash attention, causal, scale 1/32 folded into log2-domain softmax.
// One wave = one 16-row Q tile; NO cross-wave barriers. Wave w of block bx
// takes q-tile bx + 32*w (balances the causal triangle). 64-wide K chunks.
// V is pre-transposed: vt[bh*64+d][t] -> contiguous 16B B-frag loads.
// ---------------------------------------------------------------------------
__global__ __launch_bounds__(256) void attn2_k(
    const u16* __restrict__ q, const u16* __restrict__ k, const u16* __restrict__ vt,
    const float* __restrict__ xf, u16* __restrict__ y, int T, int E) {
    __shared__ u16 lds_p[4][16][72];   // +8 pad: breaks 128B-stride bank aliasing

    const int tid = threadIdx.x;
    const int lane = tid & 63, wave = tid >> 6;
    const int l15 = lane & 15, lq = lane >> 4;
    const int bh = blockIdx.y;
    const int b = bh >> 4, h = bh & 15;
    const int tile = blockIdx.x + 32 * wave;   // 0..127
    const int qt = tile * 16;

    const size_t base = (size_t)b * T * E + (size_t)h * 64;
    const u16* qp = q + base;
    const u16* kp = k + base;
    const u16* vtp = vt + (size_t)bh * 64 * T;  // [64][T]

    short8 aq[2];
#pragma unroll
    for (int c = 0; c < 2; ++c)
        aq[c] = *(const short8*)&qp[(size_t)(qt + l15) * E + c * 32 + lq * 8];

    floatx4 o[4];
#pragma unroll
    for (int n = 0; n < 4; ++n) o[n] = (floatx4)0.0f;
    float mrow[4], lrow[4];
#pragma unroll
    for (int r = 0; r < 4; ++r) { mrow[r] = -3.0e38f; lrow[r] = 0.0f; }

    const float c2 = 0.04508422f;  // log2(e)/32
    const int nkb = (qt + 16 + 63) >> 6;

    for (int kt = 0; kt < nkb; ++kt) {
        const int kc0 = kt << 6;
        const bool partial = (kc0 + 63 > qt);  // wave-uniform; only last chunk

        // S = Q K^T, 16 rows x 64 cols (4 subtiles)
        floatx4 s[4];
#pragma unroll
        for (int t2 = 0; t2 < 4; ++t2) {
            floatx4 sa = (floatx4)0.0f;
#pragma unroll
            for (int c = 0; c < 2; ++c) {
                short8 bk = *(const short8*)&kp[(size_t)(kc0 + t2 * 16 + l15) * E + c * 32 + lq * 8];
                sa = __builtin_amdgcn_mfma_f32_16x16x32_bf16(aq[c], bk, sa, 0, 0, 0);
            }
            s[t2] = sa;
        }

        // issue V B-frag loads now so they overlap the softmax VALU
        short8 bv[2][4];
#pragma unroll
        for (int kc = 0; kc < 2; ++kc)
#pragma unroll
            for (int n = 0; n < 4; ++n)
                bv[kc][n] = *(const short8*)&vtp[(size_t)(n * 16 + l15) * T + kc0 + kc * 32 + lq * 8];

        // scale into log2 domain (+ mask on the diagonal chunk)
        if (partial) {
#pragma unroll
            for (int t2 = 0; t2 < 4; ++t2)
#pragma unroll
                for (int r = 0; r < 4; ++r) {
                    int colg = kc0 + t2 * 16 + l15;
                    int rowg = qt + lq * 4 + r;
                    s[t2][r] = (colg <= rowg) ? s[t2][r] * c2 : -1.0e30f;
                }
        } else {
#pragma unroll
            for (int t2 = 0; t2 < 4; ++t2)
#pragma unroll
                for (int r = 0; r < 4; ++r) s[t2][r] *= c2;
        }

        // online softmax per q-row (rows parallel across the 4 lq groups)
#pragma unroll
        for (int r = 0; r < 4; ++r) {
            float mv = fmaxf(fmaxf(s[0][r], s[1][r]), fmaxf(s[2][r], s[3][r]));
#pragma unroll
            for (int msk = 1; msk < 16; msk <<= 1) mv = fmaxf(mv, __shfl_xor(mv, msk, 64));
            float mnew = fmaxf(mrow[r], mv);
            float alpha = EXP2F(mrow[r] - mnew);
            float p0 = EXP2F(s[0][r] - mnew);
            float p1 = EXP2F(s[1][r] - mnew);
            float p2 = EXP2F(s[2][r] - mnew);
            float p3 = EXP2F(s[3][r] - mnew);
            float sum = (p0 + p1) + (p2 + p3);
#pragma unroll
            for (int msk = 1; msk < 16; msk <<= 1) sum += __shfl_xor(sum, msk, 64);
            lrow[r] = lrow[r] * alpha + sum;
            mrow[r] = mnew;
#pragma unroll
            for (int n = 0; n < 4; ++n) o[n][r] *= alpha;
            lds_p[wave][lq * 4 + r][l15] = f2bf(p0);
            lds_p[wave][lq * 4 + r][16 + l15] = f2bf(p1);
            lds_p[wave][lq * 4 + r][32 + l15] = f2bf(p2);
            lds_p[wave][lq * 4 + r][48 + l15] = f2bf(p3);
        }
        // wave-local LDS ordering only (per-wave buffer, no cross-wave deps)
        __asm__ volatile("s_waitcnt lgkmcnt(0)" ::: "memory");

        // O += P @ V
#pragma unroll
        for (int kc = 0; kc < 2; ++kc) {
            short8 ap = *(const short8*)&lds_p[wave][l15][kc * 32 + lq * 8];
#pragma unroll
            for (int n = 0; n < 4; ++n)
                o[n] = __builtin_amdgcn_mfma_f32_16x16x32_bf16(ap, bv[kc][n], o[n], 0, 0, 0);
        }
    }

    // epilogue: y = x + O/l (bf16 out, f32 residual in)
    const float* xp = xf + base;
    u16* yp = y + base;
    float rl[4];
#pragma unroll
    for (int r = 0; r < 4; ++r) rl[r] = 1.0f / lrow[r];
#pragma unroll
    for (int n = 0; n < 4; ++n)
#pragma unroll
        for (int r = 0; r < 4; ++r) {
            int rowg = qt + lq * 4 + r;
            int col = n * 16 + l15;
            float val = o[n][r] * rl[r];
            float res = xp[(size_t)rowg * E + col];
            yp[(size_t)rowg * E + col] = f2bf(res + val);
        }
}

// ---------------------------------------------------------------------------
extern "C" void kernel_launch(void* const* d_in, const int* in_sizes, int n_in,
                              void* d_out, int out_size, void* d_ws, size_t ws_size,
                              hipStream_t stream) {
    const int B = 2, T = 2048, E = 1024;
    const int M = B * T;  // 4096

    const float* x  = (const float*)d_in[0];
    const float* Wq = (const float*)d_in[1];
    const float* Wk = (const float*)d_in[2];
    const float* Wv = (const float*)d_in[3];
    const float* Wf = (const float*)d_in[4];
    const float* bf = (const float*)d_in[5];
    float* out = (float*)d_out;

    u16* ws = (u16*)d_ws;
    const size_t WN = (size_t)E * E;      // 1M elems per weight
    const size_t XN = (size_t)M * E;      // 4M elems per activation
    u16* WqT = ws;
    u16* WkT = ws + WN;
    u16* WvT = ws + 2 * WN;
    u16* WfT = ws + 3 * WN;
    u16* xb  = ws + 4 * WN;
    u16* qb  = xb + XN;
    u16* kb  = qb + XN;
    u16* vb  = kb + XN;
    u16* yb  = vb + XN;
    u16* vt  = xb;  // alias: xb is dead after the QKV GEMMs; vt is BH*64*T = XN elems

    conv_transpose_k<<<dim3(E / 32, E / 32, 4), dim3(32, 32), 0, stream>>>(
        Wq, Wk, Wv, Wf, WqT, WkT, WvT, WfT, E);
    conv_k<<<(int)(XN / 1024), 256, 0, stream>>>(x, xb, (int)XN);

    dim3 gb(M / 128, E / 128);  // 32 x 8
    gemm_bt<0><<<gb, 256, 0, stream>>>(xb, WqT, qb, nullptr, nullptr, nullptr, M, E, E);
    gemm_bt<0><<<gb, 256, 0, stream>>>(xb, WkT, kb, nullptr, nullptr, nullptr, M, E, E);
    gemm_bt<0><<<gb, 256, 0, stream>>>(xb, WvT, vb, nullptr, nullptr, nullptr, M, E, E);

    vtrans_k<<<dim3(T / 32, 2, B * 16), dim3(32, 32), 0, stream>>>(vb, vt, T, E);

    attn2_k<<<dim3(T / 64, B * 16), 256, 0, stream>>>(qb, kb, vt, x, yb, T, E);

    gemm_bt<1><<<gb, 256, 0, stream>>>(yb, WfT, nullptr, out, bf, yb, M, E, E);
}

// Round 5
// 306.394 us; speedup vs baseline: 1.4585x; 1.1625x over previous
//
#include <hip/hip_runtime.h>
#include <cstdint>
#include <cstddef>

typedef unsigned short u16;
typedef short short8 __attribute__((ext_vector_type(8)));
typedef float floatx4 __attribute__((ext_vector_type(4)));

__device__ __forceinline__ float bf2f(u16 u) {
    union { unsigned int i; float f; } v; v.i = ((unsigned int)u) << 16; return v.f;
}
__device__ __forceinline__ u16 f2bf(float f) {
    union { float f; unsigned int i; } v; v.f = f;
    unsigned int u = v.i;
    return (u16)((u + 0x7fffu + ((u >> 16) & 1u)) >> 16);
}

#if __has_builtin(__builtin_amdgcn_exp2f)
#define EXP2F(x) __builtin_amdgcn_exp2f(x)
#else
#define EXP2F(x) exp2f(x)
#endif

// async global->LDS, 16B per lane; LDS dest = wave-uniform base + lane*16
__device__ __forceinline__ void gload_lds16(const u16* g, void* lds_wave_base) {
    __builtin_amdgcn_global_load_lds(
        (__attribute__((address_space(1))) void*)g,
        (__attribute__((address_space(3))) void*)lds_wave_base,
        16, 0, 0);
}

// ---------------------------------------------------------------------------
// Convert+transpose 4 weight matrices (E x E, f32) -> bf16. Wt[n][k]=W[k][n].
// o0..o2 are the three slices of the fused QKV Bt (consecutive), o3 = WfT.
// ---------------------------------------------------------------------------
__global__ void conv_transpose_k(const float* __restrict__ w0, const float* __restrict__ w1,
                                 const float* __restrict__ w2, const float* __restrict__ w3,
                                 u16* __restrict__ o0, u16* __restrict__ o1,
                                 u16* __restrict__ o2, u16* __restrict__ o3, int n) {
    __shared__ float t[32][33];
    const float* w; u16* o;
    switch (blockIdx.z) {
        case 0: w = w0; o = o0; break;
        case 1: w = w1; o = o1; break;
        case 2: w = w2; o = o2; break;
        default: w = w3; o = o3; break;
    }
    int tx = threadIdx.x, ty = threadIdx.y;
    int x0 = blockIdx.x * 32, y0 = blockIdx.y * 32;
    t[ty][tx] = w[(size_t)(y0 + ty) * n + x0 + tx];
    __syncthreads();
    o[(size_t)(x0 + ty) * n + y0 + tx] = f2bf(t[tx][ty]);
}

// ---------------------------------------------------------------------------
// Convert f32 -> bf16, vectorized.
// ---------------------------------------------------------------------------
__global__ void conv_k(const float* __restrict__ in, u16* __restrict__ out, int n) {
    int i = (blockIdx.x * blockDim.x + threadIdx.x) * 4;
    if (i >= n) return;
    float4 v = *(const float4*)&in[i];
    ushort4 o;
    o.x = f2bf(v.x); o.y = f2bf(v.y); o.z = f2bf(v.z); o.w = f2bf(v.w);
    *(ushort4*)&out[i] = o;
}

// ---------------------------------------------------------------------------
// Per-head V transpose from fused qkv buffer (row stride 3E, V at col 2E):
// vt[(b*16+h)*64 + d][t] = qkv[(b*T+t)*3E + 2E + h*64 + d]
// grid (T/32, 2, B*H), block (32,32)
// ---------------------------------------------------------------------------
__global__ void vtrans_k(const u16* __restrict__ qkv, u16* __restrict__ vt, int T, int E) {
    __shared__ u16 t[32][33];
    int bh = blockIdx.z;
    int b = bh >> 4, h = bh & 15;
    int t0 = blockIdx.x * 32, d0 = blockIdx.y * 32;
    int tx = threadIdx.x, ty = threadIdx.y;
    t[ty][tx] = qkv[(size_t)(b * T + t0 + ty) * (3 * E) + 2 * E + h * 64 + d0 + tx];
    __syncthreads();
    vt[((size_t)bh * 64 + d0 + ty) * T + t0 + tx] = t[tx][ty];
}

// ---------------------------------------------------------------------------
// C[M,N] = A[M,K] @ Bt[N,K]^T, bf16 in, f32 accum, bf16 out.
// 128x128 tile, BK=32, 4 waves x (4x4) 16x16x32 MFMA. global_load_lds staging.
// ---------------------------------------------------------------------------
__global__ __launch_bounds__(256) void gemm_bt(
    const u16* __restrict__ A, const u16* __restrict__ Bt, u16* __restrict__ Cb,
    int M, int N, int K) {
    __shared__ u16 lds_a[128][32];
    __shared__ u16 lds_b[128][32];

    const int tid = threadIdx.x;
    const int lane = tid & 63, wave = tid >> 6;
    const int wm = (wave >> 1) * 64, wn = (wave & 1) * 64;
    const int bm = blockIdx.x * 128, bn = blockIdx.y * 128;
    const int l15 = lane & 15, lq = lane >> 4;

    floatx4 acc[4][4];
#pragma unroll
    for (int i = 0; i < 4; ++i)
#pragma unroll
        for (int j = 0; j < 4; ++j) acc[i][j] = (floatx4)0.0f;

    for (int k0 = 0; k0 < K; k0 += 32) {
#pragma unroll
        for (int it = 0; it < 2; ++it) {
            int idx = it * 256 + tid;        // 0..511
            int row = idx >> 2;              // 0..127
            int c8 = (idx & 3) * 8;          // 0,8,16,24
            size_t ldsoff = (size_t)(it * 256 + wave * 64) * 16;  // bytes, wave-uniform
            gload_lds16(&A[(size_t)(bm + row) * K + k0 + c8], (char*)&lds_a[0][0] + ldsoff);
            gload_lds16(&Bt[(size_t)(bn + row) * K + k0 + c8], (char*)&lds_b[0][0] + ldsoff);
        }
        __syncthreads();

        short8 af[4], bfr[4];
#pragma unroll
        for (int i = 0; i < 4; ++i) af[i] = *(const short8*)&lds_a[wm + i * 16 + l15][lq * 8];
#pragma unroll
        for (int j = 0; j < 4; ++j) bfr[j] = *(const short8*)&lds_b[wn + j * 16 + l15][lq * 8];

#pragma unroll
        for (int i = 0; i < 4; ++i)
#pragma unroll
            for (int j = 0; j < 4; ++j)
                acc[i][j] = __builtin_amdgcn_mfma_f32_16x16x32_bf16(af[i], bfr[j], acc[i][j], 0, 0, 0);
        __syncthreads();
    }

#pragma unroll
    for (int i = 0; i < 4; ++i)
#pragma unroll
        for (int j = 0; j < 4; ++j)
#pragma unroll
            for (int r = 0; r < 4; ++r) {
                int row = bm + wm + i * 16 + lq * 4 + r;
                int col = bn + wn + j * 16 + l15;
                Cb[(size_t)row * N + col] = f2bf(acc[i][j][r]);
            }
}

// ---------------------------------------------------------------------------
// FF GEMM: 64x128 tile (512 blocks -> 2/CU at M=4096,N=1024). 4 waves, each
// 32x64 (2x4 MFMA tiles). Cf (f32) = bf2f(resid) + relu(acc + bias[col]).
// ---------------------------------------------------------------------------
__global__ __launch_bounds__(256) void gemm64_bt(
    const u16* __restrict__ A, const u16* __restrict__ Bt, float* __restrict__ Cf,
    const float* __restrict__ bias, const u16* __restrict__ resid,
    int M, int N, int K) {
    __shared__ u16 lds_a[64][32];
    __shared__ u16 lds_b[128][32];

    const int tid = threadIdx.x;
    const int lane = tid & 63, wave = tid >> 6;
    const int wm = (wave >> 1) * 32, wn = (wave & 1) * 64;
    const int bm = blockIdx.x * 64, bn = blockIdx.y * 128;
    const int l15 = lane & 15, lq = lane >> 4;

    floatx4 acc[2][4];
#pragma unroll
    for (int i = 0; i < 2; ++i)
#pragma unroll
        for (int j = 0; j < 4; ++j) acc[i][j] = (floatx4)0.0f;

    for (int k0 = 0; k0 < K; k0 += 32) {
        {
            int row = tid >> 2;              // 0..63
            int c8 = (tid & 3) * 8;
            size_t ldsoff = (size_t)(wave * 64) * 16;
            gload_lds16(&A[(size_t)(bm + row) * K + k0 + c8], (char*)&lds_a[0][0] + ldsoff);
        }
#pragma unroll
        for (int it = 0; it < 2; ++it) {
            int idx = it * 256 + tid;
            int row = idx >> 2;              // 0..127
            int c8 = (idx & 3) * 8;
            size_t ldsoff = (size_t)(it * 256 + wave * 64) * 16;
            gload_lds16(&Bt[(size_t)(bn + row) * K + k0 + c8], (char*)&lds_b[0][0] + ldsoff);
        }
        __syncthreads();

        short8 af[2], bfr[4];
#pragma unroll
        for (int i = 0; i < 2; ++i) af[i] = *(const short8*)&lds_a[wm + i * 16 + l15][lq * 8];
#pragma unroll
        for (int j = 0; j < 4; ++j) bfr[j] = *(const short8*)&lds_b[wn + j * 16 + l15][lq * 8];

#pragma unroll
        for (int i = 0; i < 2; ++i)
#pragma unroll
            for (int j = 0; j < 4; ++j)
                acc[i][j] = __builtin_amdgcn_mfma_f32_16x16x32_bf16(af[i], bfr[j], acc[i][j], 0, 0, 0);
        __syncthreads();
    }

#pragma unroll
    for (int i = 0; i < 2; ++i)
#pragma unroll
        for (int j = 0; j < 4; ++j)
#pragma unroll
            for (int r = 0; r < 4; ++r) {
                int row = bm + wm + i * 16 + lq * 4 + r;
                int col = bn + wn + j * 16 + l15;
                float v = acc[i][j][r];
                v = fmaxf(v + bias[col], 0.0f) + bf2f(resid[(size_t)row * N + col]);
                Cf[(size_t)row * N + col] = v;
            }
}

// ---------------------------------------------------------------------------
// Flash attention, causal, scale 1/32 folded into log2-domain softmax.
// Block = 2 waves (128 thr). Wave 0 of block bx takes q-tile bx, wave 1 takes
// tile 127-bx -> constant work per block (causal balance). grid.x = 64 covers
// all 128 tiles. No cross-wave barriers. q/k from fused qkv (row stride 3E);
// V pre-transposed.
// ---------------------------------------------------------------------------
__global__ __launch_bounds__(128) void attn3_k(
    const u16* __restrict__ qkv, const u16* __restrict__ vt,
    const float* __restrict__ xf, u16* __restrict__ y, int T, int E) {
    __shared__ u16 lds_p[2][16][72];   // per-wave P buffer, padded

    const int tid = threadIdx.x;
    const int lane = tid & 63, wave = tid >> 6;
    const int l15 = lane & 15, lq = lane >> 4;
    const int bh = blockIdx.y;
    const int b = bh >> 4, h = bh & 15;
    const int tile = wave ? (127 - blockIdx.x) : blockIdx.x;   // bx in 0..63 -> tiles 0..127
    const int qt = tile * 16;
    const int S3 = 3 * E;

    const u16* qp = qkv + (size_t)b * T * S3 + (size_t)h * 64;
    const u16* kp = qp + E;
    const u16* vtp = vt + (size_t)bh * 64 * T;  // [64][T]

    short8 aq[2];
#pragma unroll
    for (int c = 0; c < 2; ++c)
        aq[c] = *(const short8*)&qp[(size_t)(qt + l15) * S3 + c * 32 + lq * 8];

    floatx4 o[4];
#pragma unroll
    for (int n = 0; n < 4; ++n) o[n] = (floatx4)0.0f;
    float mrow[4], lrow[4];
#pragma unroll
    for (int r = 0; r < 4; ++r) { mrow[r] = -3.0e38f; lrow[r] = 0.0f; }

    const float c2 = 0.04508422f;  // log2(e)/32
    const int nkb = (qt + 16 + 63) >> 6;

    for (int kt = 0; kt < nkb; ++kt) {
        const int kc0 = kt << 6;
        const bool partial = (kc0 + 63 > qt);  // wave-uniform; only last chunk

        // S = Q K^T, 16 rows x 64 cols (4 subtiles)
        floatx4 s[4];
#pragma unroll
        for (int t2 = 0; t2 < 4; ++t2) {
            floatx4 sa = (floatx4)0.0f;
#pragma unroll
            for (int c = 0; c < 2; ++c) {
                short8 bk = *(const short8*)&kp[(size_t)(kc0 + t2 * 16 + l15) * S3 + c * 32 + lq * 8];
                sa = __builtin_amdgcn_mfma_f32_16x16x32_bf16(aq[c], bk, sa, 0, 0, 0);
            }
            s[t2] = sa;
        }

        // issue V B-frag loads now so they overlap the softmax VALU
        short8 bv[2][4];
#pragma unroll
        for (int kc = 0; kc < 2; ++kc)
#pragma unroll
            for (int n = 0; n < 4; ++n)
                bv[kc][n] = *(const short8*)&vtp[(size_t)(n * 16 + l15) * T + kc0 + kc * 32 + lq * 8];

        // scale into log2 domain (+ mask on the diagonal chunk)
        if (partial) {
#pragma unroll
            for (int t2 = 0; t2 < 4; ++t2)
#pragma unroll
                for (int r = 0; r < 4; ++r) {
                    int colg = kc0 + t2 * 16 + l15;
                    int rowg = qt + lq * 4 + r;
                    s[t2][r] = (colg <= rowg) ? s[t2][r] * c2 : -1.0e30f;
                }
        } else {
#pragma unroll
            for (int t2 = 0; t2 < 4; ++t2)
#pragma unroll
                for (int r = 0; r < 4; ++r) s[t2][r] *= c2;
        }

        // online softmax per q-row (rows parallel across the 4 lq groups)
#pragma unroll
        for (int r = 0; r < 4; ++r) {
            float mv = fmaxf(fmaxf(s[0][r], s[1][r]), fmaxf(s[2][r], s[3][r]));
#pragma unroll
            for (int msk = 1; msk < 16; msk <<= 1) mv = fmaxf(mv, __shfl_xor(mv, msk, 64));
            float mnew = fmaxf(mrow[r], mv);
            float alpha = EXP2F(mrow[r] - mnew);
            float p0 = EXP2F(s[0][r] - mnew);
            float p1 = EXP2F(s[1][r] - mnew);
            float p2 = EXP2F(s[2][r] - mnew);
            float p3 = EXP2F(s[3][r] - mnew);
            float sum = (p0 + p1) + (p2 + p3);
#pragma unroll
            for (int msk = 1; msk < 16; msk <<= 1) sum += __shfl_xor(sum, msk, 64);
            lrow[r] = lrow[r] * alpha + sum;
            mrow[r] = mnew;
#pragma unroll
            for (int n = 0; n < 4; ++n) o[n][r] *= alpha;
            lds_p[wave][lq * 4 + r][l15] = f2bf(p0);
            lds_p[wave][lq * 4 + r][16 + l15] = f2bf(p1);
            lds_p[wave][lq * 4 + r][32 + l15] = f2bf(p2);
            lds_p[wave][lq * 4 + r][48 + l15] = f2bf(p3);
        }
        // wave-local LDS ordering only (per-wave buffer, no cross-wave deps)
        __asm__ volatile("s_waitcnt lgkmcnt(0)" ::: "memory");

        // O += P @ V
#pragma unroll
        for (int kc = 0; kc < 2; ++kc) {
            short8 ap = *(const short8*)&lds_p[wave][l15][kc * 32 + lq * 8];
#pragma unroll
            for (int n = 0; n < 4; ++n)
                o[n] = __builtin_amdgcn_mfma_f32_16x16x32_bf16(ap, bv[kc][n], o[n], 0, 0, 0);
        }
    }

    // epilogue: y = x + O/l (bf16 out, f32 residual in)
    const float* xp = xf + (size_t)b * T * E + (size_t)h * 64;
    u16* yp = y + (size_t)b * T * E + (size_t)h * 64;
    float rl[4];
#pragma unroll
    for (int r = 0; r < 4; ++r) rl[r] = 1.0f / lrow[r];
#pragma unroll
    for (int n = 0; n < 4; ++n)
#pragma unroll
        for (int r = 0; r < 4; ++r) {
            int rowg = qt + lq * 4 + r;
            int col = n * 16 + l15;
            float val = o[n][r] * rl[r];
            float res = xp[(size_t)rowg * E + col];
            yp[(size_t)rowg * E + col] = f2bf(res + val);
        }
}

// ---------------------------------------------------------------------------
extern "C" void kernel_launch(void* const* d_in, const int* in_sizes, int n_in,
                              void* d_out, int out_size, void* d_ws, size_t ws_size,
                              hipStream_t stream) {
    const int B = 2, T = 2048, E = 1024;
    const int M = B * T;  // 4096

    const float* x  = (const float*)d_in[0];
    const float* Wq = (const float*)d_in[1];
    const float* Wk = (const float*)d_in[2];
    const float* Wv = (const float*)d_in[3];
    const float* Wf = (const float*)d_in[4];
    const float* bf = (const float*)d_in[5];
    float* out = (float*)d_out;

    u16* ws = (u16*)d_ws;
    const size_t WN = (size_t)E * E;      // 1M elems per weight
    const size_t XN = (size_t)M * E;      // 4M elems per activation
    u16* Wqkv = ws;                        // [3E][E] fused transposed weights
    u16* WfT  = ws + 3 * WN;
    u16* xb   = ws + 4 * WN;               // aliased by vt after QKV GEMM
    u16* qkv  = ws + 4 * WN + XN;          // [M][3E] = 3*XN elems
    u16* yb   = ws + 4 * WN + 4 * XN;
    u16* vt   = xb;                        // BH*64*T = XN elems

    conv_transpose_k<<<dim3(E / 32, E / 32, 4), dim3(32, 32), 0, stream>>>(
        Wq, Wk, Wv, Wf, Wqkv, Wqkv + WN, Wqkv + 2 * WN, WfT, E);
    conv_k<<<(int)(XN / 1024), 256, 0, stream>>>(x, xb, (int)XN);

    // fused QKV projection: [M,E] @ [E,3E] -> [M,3E]
    gemm_bt<<<dim3(M / 128, 3 * E / 128), 256, 0, stream>>>(xb, Wqkv, qkv, M, 3 * E, E);

    vtrans_k<<<dim3(T / 32, 2, B * 16), dim3(32, 32), 0, stream>>>(qkv, vt, T, E);

    // 128 q-tiles, 2 waves/block -> 64 blocks in x (FIX: was /32/2 = 32)
    attn3_k<<<dim3(T / 16 / 2, B * 16), 128, 0, stream>>>(qkv, vt, x, yb, T, E);

    // FF: out = yb + relu(yb @ Wf + bf)
    gemm64_bt<<<dim3(M / 64, E / 128), 256, 0, stream>>>(yb, WfT, out, bf, yb, M, E, E);
}